// Round 14
// baseline (1674.053 us; speedup 1.0000x reference)
//
#include <hip/hip_runtime.h>

// Problem constants
#define BB 4
#define SS 32
#define CC 128
#define HH 16
#define WW 32
#define HID 128
#define DEPTH 2
#define CIN 256           // CC + HID
#define COUT 512          // 4*HID
#define K9 (CIN * 9)      // 2304
#define KH 1152           // per-source K: tap-major k = tap*128 + ch
#define KFULL (2 * KH)    // 2304 = x-part rows then h-part rows
#define HW (HH * WW)      // 512
#define MM (BB * HW)      // 2048
#define ACT (BB * HW * 128) // 262144 = one activation slice (b,hw,ch)

typedef __attribute__((ext_vector_type(4))) float f32x4;
typedef __attribute__((ext_vector_type(16))) float f32x16;
typedef __attribute__((ext_vector_type(8))) short bf16x8;

static __device__ __forceinline__ unsigned short f2bf(float f) {
    union { float f; unsigned u; } v; v.f = f;
    unsigned r = v.u + 0x7FFF + ((v.u >> 16) & 1);   // RNE
    return (unsigned short)(r >> 16);
}
static __device__ __forceinline__ float bf2f(unsigned short h) {
    union { float f; unsigned u; } v; v.u = ((unsigned)h) << 16; return v.f;
}

// ---------------------------------------------------------------------------
// Weight transpose -> separate hi/lo bf16 planes, k-major:
//   wh/wl [DEPTH][COUT_g][KFULL] ushort
// k row: cin<CC -> tap*CC+cin (x block) else KH + tap*HID + (cin-CC) (h block)
// n gate-gathered: n' = (r>>4)*64 + g*16 + (r&15)
// ---------------------------------------------------------------------------
__global__ void transpose_w_kernel(const float* __restrict__ w,
                                   unsigned short* __restrict__ wh,
                                   unsigned short* __restrict__ wl) {
    int idx = blockIdx.x * 256 + threadIdx.x;
    if (idx >= DEPTH * K9 * COUT) return;
    int n = idx % COUT;
    int k = (idx / COUT) % K9;
    int d = idx / (COUT * K9);
    int cin = k / 9, tap = k % 9;
    float v = w[(((long)(d * COUT + n) * CIN + cin) * 9) + tap];
    int row = (cin < CC) ? (tap * CC + cin) : (KH + tap * HID + (cin - CC));
    int g = n >> 7, r = n & 127;
    int ng = (r >> 4) * 64 + g * 16 + (r & 15);
    unsigned short hi = f2bf(v);
    unsigned short lo = f2bf(v - bf2f(hi));
    long o = ((long)d * COUT + ng) * KFULL + row;
    wh[o] = hi;
    wl[o] = lo;
}

// ---------------------------------------------------------------------------
// Pack x [B][S][CC][HW] fp32 -> hi/lo planes [s][b][hw][cc] via LDS transpose.
// grid (SS*BB, HW/64), 256 threads. Coalesced reads (float2 along hw) and
// coalesced u32 writes (along cc).
// ---------------------------------------------------------------------------
__global__ void pack_x_kernel(const float* __restrict__ x,
                              unsigned* __restrict__ xh32,
                              unsigned* __restrict__ xl32) {
    __shared__ unsigned lh[128 * 33], ll[128 * 33];   // [cc][hw-pair], pad 33
    const int tid = threadIdx.x;
    const int sb  = blockIdx.x;          // s*BB + b
    const int s   = sb >> 2;
    const int b   = sb & 3;
    const int hw0 = blockIdx.y * 64;
    const float* src = x + ((long)(b * SS + s) * CC) * HW;

    #pragma unroll
    for (int it = 0; it < 16; ++it) {
        int cc = it * 8 + (tid >> 5);
        int hw = (tid & 31) * 2;
        float2 v = *(const float2*)&src[cc * HW + hw0 + hw];
        unsigned short h0 = f2bf(v.x), h1 = f2bf(v.y);
        unsigned short l0 = f2bf(v.x - bf2f(h0)), l1 = f2bf(v.y - bf2f(h1));
        lh[cc * 33 + (hw >> 1)] = (unsigned)h0 | ((unsigned)h1 << 16);
        ll[cc * 33 + (hw >> 1)] = (unsigned)l0 | ((unsigned)l1 << 16);
    }
    __syncthreads();
    const unsigned short* lhs = (const unsigned short*)lh;
    const unsigned short* lls = (const unsigned short*)ll;
    #pragma unroll
    for (int it = 0; it < 16; ++it) {
        int hw = it * 4 + (tid >> 6);
        int c2 = tid & 63;               // cc pair
        unsigned short a0 = lhs[(2 * c2) * 66 + hw];
        unsigned short a1 = lhs[(2 * c2 + 1) * 66 + hw];
        unsigned short b0 = lls[(2 * c2) * 66 + hw];
        unsigned short b1 = lls[(2 * c2 + 1) * 66 + hw];
        long o = ((long)sb * HW + hw0 + hw) * 64 + c2;
        xh32[o] = (unsigned)a0 | ((unsigned)a1 << 16);
        xl32[o] = (unsigned)b0 | ((unsigned)b1 << 16);
    }
}

// ---------------------------------------------------------------------------
// Broadcast init_h/init_c[d] into hi/lo h planes ([b][hw][hid]) + fp32 c
// ---------------------------------------------------------------------------
__global__ void init_state_kernel(const float* __restrict__ ih, const float* __restrict__ ic,
                                  unsigned short* __restrict__ hh, unsigned short* __restrict__ hl,
                                  float* __restrict__ c, int d) {
    int idx = blockIdx.x * 256 + threadIdx.x;   // ACT = 262144
    int hid = idx & 127;
    float v = ih[d * HID + hid];
    unsigned short hi = f2bf(v);
    hh[idx] = hi;
    hl[idx] = f2bf(v - bf2f(hi));
    c[idx] = ic[d * HID + hid];
}

// Zero the 256B OOB page (workspace is poisoned 0xAA before timing)
__global__ void zero_kernel(unsigned* __restrict__ zp) { zp[threadIdx.x] = 0u; }

// ---------------------------------------------------------------------------
// DUAL-LAYER fused step kernel — 32x32x16 MFMA version.
// M=64, N=64 per wg, 256 threads = 4 waves (2m x 2n of 32x32). BK=64 tiles,
// hi/lo planes pre-split, XOR-swizzled LDS (conflict-free b128), single
// barrier per tile, two alternating accumulators (break MFMA dep chain),
// setprio around MFMA cluster. Grid 512 flat, XCD-stable swizzle.
// K = 36 tiles: tt<18 from x-source, tt>=18 from h-source (tap-major).
// ---------------------------------------------------------------------------
__launch_bounds__(256)
__global__ void step_dual(
    const unsigned short* __restrict__ x1h, const unsigned short* __restrict__ x1l,
    const unsigned short* __restrict__ h1h, const unsigned short* __restrict__ h1l,
    float* __restrict__ c1, unsigned short* __restrict__ o1h, unsigned short* __restrict__ o1l,
    const unsigned short* __restrict__ x2h, const unsigned short* __restrict__ x2l,
    const unsigned short* __restrict__ h2h, const unsigned short* __restrict__ h2l,
    float* __restrict__ c2, unsigned short* __restrict__ o2h, unsigned short* __restrict__ o2l,
    const unsigned short* __restrict__ wh, const unsigned short* __restrict__ wl,
    const float* __restrict__ bias, const unsigned short* __restrict__ zp,
    int do1, int do2)
{
    // buf layout (ushort idx): A_hi [0,4096) rows m*64+k, A_lo [4096,8192),
    // B_hi [8192,12288), B_lo [12288,16384). 2 bufs = 64 KB.
    __shared__ __align__(16) unsigned short lds[2][16384];

    const int bid  = blockIdx.x;
    const int xcd  = bid & 7;
    const int q    = bid >> 3;               // 0..63
    const int mblk = q & 31;
    const int pp   = xcd + ((q >> 5) << 3);  // panel 0..15
    const int nblk = pp & 7;
    const int z    = pp >> 3;
    if (z == 0) { if (!do1) return; } else { if (!do2) return; }

    const unsigned short* axh = z ? x2h : x1h;
    const unsigned short* axl = z ? x2l : x1l;
    const unsigned short* ahh = z ? h2h : h1h;
    const unsigned short* ahl = z ? h2l : h1l;
    const unsigned short* wph = wh + (long)z * COUT * KFULL;
    const unsigned short* wpl = wl + (long)z * COUT * KFULL;
    const float* bsel  = bias + z * COUT;
    float* csel        = z ? c2 : c1;
    unsigned short* ohh = z ? o2h : o1h;
    unsigned short* ohl = z ? o2l : o1l;

    const int m0   = mblk * 64;
    const int n0g  = nblk * 64;
    const int hid0 = nblk * 16;
    const int tid  = threadIdx.x;
    const int lane = tid & 63;
    const int wv   = tid >> 6;              // wave 0..3
    const int wm   = (wv >> 1) * 32;        // wave m offset
    const int wn   = (wv & 1) * 32;         // wave n offset
    const int b    = m0 >> 9;
    const int hwl  = m0 & 511;
    const int y0   = hwl >> 5;              // first image row (2 rows per wg)

    // staging: thread t: row r = t>>2 (0..63), chunks j0 = t&3, j1 = j0+4;
    // source chunk = j ^ (r&7) (XOR swizzle), LDS chunk = j (linear)
    const int r    = tid >> 2;
    const int j0   = tid & 3;
    const int jx0  = j0 ^ (r & 7);
    const int jx1  = (j0 + 4) ^ (r & 7);
    const int sx   = r & 31;
    const int sy   = y0 + (r >> 5);
    const long bhw = (long)b * HW;
    const long bofs = (long)(n0g + r) * KFULL;
    const int seg0 = r * 64 + j0 * 8;
    const int seg1 = seg0 + 32;

    uint4 rah0, rah1, ral0, ral1, rbh0, rbh1, rbl0, rbl1;
    auto ld = [&](int tt) {
        const int k0 = tt * 64;
        rbh0 = *(const uint4*)(wph + bofs + k0 + jx0 * 8);
        rbh1 = *(const uint4*)(wph + bofs + k0 + jx1 * 8);
        rbl0 = *(const uint4*)(wpl + bofs + k0 + jx0 * 8);
        rbl1 = *(const uint4*)(wpl + bofs + k0 + jx1 * 8);
        int ksub = (tt < 18) ? tt : tt - 18;
        int tap  = ksub >> 1;
        int c0   = (ksub & 1) << 6;
        int ky   = tap / 3 - 1;
        int kx   = tap - (tap / 3) * 3 - 1;
        int yy   = sy + ky;
        int xq   = sx + kx;
        bool ok  = (unsigned)yy < (unsigned)HH && (unsigned)xq < (unsigned)WW;
        long abase = ((bhw + yy * WW + xq) << 7) + c0;
        const unsigned short* sh = (tt < 18) ? axh : ahh;
        const unsigned short* sl = (tt < 18) ? axl : ahl;
        const unsigned short* p0h = ok ? sh + abase + jx0 * 8 : zp;
        const unsigned short* p1h = ok ? sh + abase + jx1 * 8 : zp;
        const unsigned short* p0l = ok ? sl + abase + jx0 * 8 : zp;
        const unsigned short* p1l = ok ? sl + abase + jx1 * 8 : zp;
        rah0 = *(const uint4*)p0h; rah1 = *(const uint4*)p1h;
        ral0 = *(const uint4*)p0l; ral1 = *(const uint4*)p1l;
    };
    auto commit = [&](int pb) {
        *(uint4*)&lds[pb][seg0]         = rah0;
        *(uint4*)&lds[pb][seg1]         = rah1;
        *(uint4*)&lds[pb][4096 + seg0]  = ral0;
        *(uint4*)&lds[pb][4096 + seg1]  = ral1;
        *(uint4*)&lds[pb][8192 + seg0]  = rbh0;
        *(uint4*)&lds[pb][8192 + seg1]  = rbh1;
        *(uint4*)&lds[pb][12288 + seg0] = rbl0;
        *(uint4*)&lds[pb][12288 + seg1] = rbl1;
    };

    f32x16 accA = (f32x16){0.f,0.f,0.f,0.f,0.f,0.f,0.f,0.f,0.f,0.f,0.f,0.f,0.f,0.f,0.f,0.f};
    f32x16 accB = (f32x16){0.f,0.f,0.f,0.f,0.f,0.f,0.f,0.f,0.f,0.f,0.f,0.f,0.f,0.f,0.f,0.f};

    // 32x32x16 fragments: row/col = lane&31, k = kstep*16 + (lane>>5)*8
    const int fcol  = lane & 31;
    const int chalf = lane >> 5;            // k-chunk half
    const int am = wm + fcol;               // A row
    const int bn = wn + fcol;               // B row (n)

    ld(0); commit(0);
    __syncthreads();
    int p = 0;
    for (int tt = 0; tt < 36; ++tt) {
        const bool more = (tt + 1 < 36);
        if (more) ld(tt + 1);               // loads in flight during compute
        const unsigned short* L = &lds[p][0];
        __builtin_amdgcn_s_setprio(1);
        #pragma unroll
        for (int s = 0; s < 4; ++s) {       // 4 k-steps of 16
            const int ca = s * 2 + chalf;   // chunk 0..7
            bf16x8 ahv = *(const bf16x8*)&L[am * 64 + ((ca ^ (am & 7)) << 3)];
            bf16x8 alv = *(const bf16x8*)&L[4096 + am * 64 + ((ca ^ (am & 7)) << 3)];
            bf16x8 bhv = *(const bf16x8*)&L[8192 + bn * 64 + ((ca ^ (bn & 7)) << 3)];
            bf16x8 blv = *(const bf16x8*)&L[12288 + bn * 64 + ((ca ^ (bn & 7)) << 3)];
            if (s & 1) {
                accB = __builtin_amdgcn_mfma_f32_32x32x16_bf16(ahv, bhv, accB, 0, 0, 0);
                accB = __builtin_amdgcn_mfma_f32_32x32x16_bf16(ahv, blv, accB, 0, 0, 0);
                accB = __builtin_amdgcn_mfma_f32_32x32x16_bf16(alv, bhv, accB, 0, 0, 0);
            } else {
                accA = __builtin_amdgcn_mfma_f32_32x32x16_bf16(ahv, bhv, accA, 0, 0, 0);
                accA = __builtin_amdgcn_mfma_f32_32x32x16_bf16(ahv, blv, accA, 0, 0, 0);
                accA = __builtin_amdgcn_mfma_f32_32x32x16_bf16(alv, bhv, accA, 0, 0, 0);
            }
        }
        __builtin_amdgcn_s_setprio(0);
        if (more) commit(1 - p);            // write NEXT buffer after compute
        __syncthreads();                    // one barrier per tile
        p ^= 1;
    }

    // --- epilogue: z-tile via LDS (reuse buffer 0), then LSTM cell update ---
    f32x16 acc;
    #pragma unroll
    for (int i = 0; i < 16; ++i) acc[i] = accA[i] + accB[i];
    float* zt = (float*)&lds[0][0];         // [64 n_gathered][68 m]
    {
        // C/D layout (m101): col = lane&31 (n), row = (reg&3)+8*(reg>>2)+4*(lane>>5)
        const int cn  = lane & 31;
        const int rb2 = (lane >> 5) * 4;
        #pragma unroll
        for (int g = 0; g < 4; ++g) {
            float4 v = make_float4(acc[4*g], acc[4*g+1], acc[4*g+2], acc[4*g+3]);
            *(float4*)&zt[(wn + cn) * 68 + wm + 8 * g + rb2] = v;
        }
    }
    __syncthreads();

    #pragma unroll
    for (int i2 = 0; i2 < 4; ++i2) {        // 1024 cell elems, 4/thread
        int e  = i2 * 256 + tid;
        int m  = e & 63;
        int jh = e >> 6;                    // hid slice 0..15
        float g4[4];
        #pragma unroll
        for (int gi = 0; gi < 4; ++gi)
            g4[gi] = zt[(gi * 16 + jh) * 68 + m] + bsel[gi * 128 + hid0 + jh];
        long idx = ((long)b * HW + hwl + m) * 128 + hid0 + jh;
        float si = 1.f / (1.f + expf(-g4[0]));
        float sf = 1.f / (1.f + expf(-g4[1]));
        float so = 1.f / (1.f + expf(-g4[3]));
        float cs = sf * csel[idx] + si * tanhf(g4[2]);
        float hs = so * tanhf(cs);
        csel[idx] = cs;
        unsigned short hi = f2bf(hs);
        ohh[idx] = hi;
        ohl[idx] = f2bf(hs - bf2f(hi));
    }
}

// ---------------------------------------------------------------------------
// Mean pool over HW: seq2 planes [s][b][hw][hid] -> pooled [(s*BB+b)*HID + j]
// ---------------------------------------------------------------------------
__global__ void pool_kernel(const unsigned short* __restrict__ s2h,
                            const unsigned short* __restrict__ s2l,
                            float* __restrict__ pooled) {
    int bs = blockIdx.x;            // s*BB + b
    int j  = threadIdx.x;           // 0..127
    const unsigned short* ph = s2h + (long)bs * HW * 128 + j;
    const unsigned short* pl = s2l + (long)bs * HW * 128 + j;
    float sum = 0.f;
    #pragma unroll 8
    for (int hw = 0; hw < HW; ++hw)
        sum += bf2f(ph[hw * 128]) + bf2f(pl[hw * 128]);
    pooled[bs * HID + j] = sum * (1.f / HW);
}

// ---------------------------------------------------------------------------
// FC + ReLU + two scalar heads.
// ---------------------------------------------------------------------------
__global__ void head_kernel(const float* __restrict__ pooled,
                            const float* __restrict__ fc_w, const float* __restrict__ fc_b,
                            const float* __restrict__ fco_w, const float* __restrict__ fco_b,
                            const float* __restrict__ fca_w, const float* __restrict__ fca_b,
                            float* __restrict__ out) {
    int bs = blockIdx.x;          // b*S + s
    int b  = bs / SS;
    int s  = bs % SS;
    int j  = threadIdx.x;
    const float* prow = pooled + (long)(s * BB + b) * HID;
    float acc = fc_b[j];
    #pragma unroll 4
    for (int k = 0; k < HID; ++k) acc += fc_w[j * HID + k] * prow[k];
    float f = fmaxf(acc, 0.f);
    __shared__ float ro[128], ra[128];
    ro[j] = f * fco_w[j];
    ra[j] = f * fca_w[j];
    __syncthreads();
    for (int off = 64; off; off >>= 1) {
        if (j < off) { ro[j] += ro[j + off]; ra[j] += ra[j + off]; }
        __syncthreads();
    }
    if (j == 0) {
        out[bs]           = ro[0] + fco_b[0];
        out[BB * SS + bs] = ra[0] + fca_b[0];
    }
}

// ---------------------------------------------------------------------------
extern "C" void kernel_launch(void* const* d_in, const int* in_sizes, int n_in,
                              void* d_out, int out_size, void* d_ws, size_t ws_size,
                              hipStream_t stream) {
    const float* x      = (const float*)d_in[0];
    const float* conv_w = (const float*)d_in[1];
    const float* conv_b = (const float*)d_in[2];
    const float* init_h = (const float*)d_in[3];
    const float* init_c = (const float*)d_in[4];
    const float* fc_w   = (const float*)d_in[5];
    const float* fc_b   = (const float*)d_in[6];
    const float* fco_w  = (const float*)d_in[7];
    const float* fco_b  = (const float*)d_in[8];
    const float* fca_w  = (const float*)d_in[9];
    const float* fca_b  = (const float*)d_in[10];
    float* out = (float*)d_out;

    // Workspace carve-up (ushort planes first, then fp32) — total ~114 MB.
    unsigned short* wh  = (unsigned short*)d_ws;            // 2,359,296
    unsigned short* wl  = wh  + (long)DEPTH * COUT * KFULL; // 2,359,296
    unsigned short* xph = wl  + (long)DEPTH * COUT * KFULL; // SS*ACT = 8,388,608
    unsigned short* xpl = xph + (long)SS * ACT;
    unsigned short* s1h = xpl + (long)SS * ACT;
    unsigned short* s1l = s1h + (long)SS * ACT;
    unsigned short* s2h = s1l + (long)SS * ACT;
    unsigned short* s2l = s2h + (long)SS * ACT;
    unsigned short* h1h = s2l + (long)SS * ACT;             // ACT each
    unsigned short* h1l = h1h + ACT;
    unsigned short* h2h = h1l + ACT;
    unsigned short* h2l = h2h + ACT;
    float* c1     = (float*)(h2l + ACT);                    // ACT f32
    float* c2     = c1 + ACT;
    float* pooled = c2 + ACT;                               // 16,384
    unsigned short* zp = (unsigned short*)(pooled + SS * BB * HID); // 256 B zeros

    transpose_w_kernel<<<(DEPTH * K9 * COUT + 255) / 256, 256, 0, stream>>>(conv_w, wh, wl);
    pack_x_kernel<<<dim3(SS * BB, HW / 64), 256, 0, stream>>>(x, (unsigned*)xph, (unsigned*)xpl);
    init_state_kernel<<<ACT / 256, 256, 0, stream>>>(init_h, init_c, h1h, h1l, c1, 0);
    init_state_kernel<<<ACT / 256, 256, 0, stream>>>(init_h, init_c, h2h, h2l, c2, 1);
    zero_kernel<<<1, 64, 0, stream>>>((unsigned*)zp);

    for (int t = 0; t <= SS; ++t) {
        int do1 = (t < SS) ? 1 : 0;
        int do2 = (t >= 1) ? 1 : 0;
        int t1 = (t < SS) ? t : SS - 1;          // clamped for safe ptr arith
        int u2 = (t >= 1) ? t - 1 : 0;
        const unsigned short* ax1h = xph + (long)t1 * ACT;
        const unsigned short* ax1l = xpl + (long)t1 * ACT;
        const unsigned short* ah1h = (t1 == 0) ? h1h : s1h + (long)(t1 - 1) * ACT;
        const unsigned short* ah1l = (t1 == 0) ? h1l : s1l + (long)(t1 - 1) * ACT;
        unsigned short* ao1h = s1h + (long)t1 * ACT;
        unsigned short* ao1l = s1l + (long)t1 * ACT;
        const unsigned short* ax2h = s1h + (long)u2 * ACT;
        const unsigned short* ax2l = s1l + (long)u2 * ACT;
        const unsigned short* ah2h = (u2 == 0) ? h2h : s2h + (long)(u2 - 1) * ACT;
        const unsigned short* ah2l = (u2 == 0) ? h2l : s2l + (long)(u2 - 1) * ACT;
        unsigned short* ao2h = s2h + (long)u2 * ACT;
        unsigned short* ao2l = s2l + (long)u2 * ACT;
        step_dual<<<512, 256, 0, stream>>>(
            ax1h, ax1l, ah1h, ah1l, c1, ao1h, ao1l,
            ax2h, ax2l, ah2h, ah2l, c2, ao2h, ao2l,
            wh, wl, conv_b, zp, do1, do2);
    }

    pool_kernel<<<SS * BB, 128, 0, stream>>>(s2h, s2l, pooled);
    head_kernel<<<BB * SS, 128, 0, stream>>>(pooled, fc_w, fc_b, fco_w, fco_b, fca_w, fca_b, out);
}

// Round 15
// 1541.986 us; speedup vs baseline: 1.0856x; 1.0856x over previous
//
#include <hip/hip_runtime.h>

// Problem constants
#define BB 4
#define SS 32
#define CC 128
#define HH 16
#define WW 32
#define HID 128
#define DEPTH 2
#define CIN 256           // CC + HID
#define COUT 512          // 4*HID
#define K9 (CIN * 9)      // 2304
#define KH 1152           // per-source K: tap-major k = tap*128 + ch
#define KFULL (2 * KH)    // 2304 = x-part rows then h-part rows
#define HW (HH * WW)      // 512
#define MM (BB * HW)      // 2048
#define ACT (BB * HW * 128) // 262144 = one activation slice (b,hw,ch)

typedef __attribute__((ext_vector_type(4))) float f32x4;
typedef __attribute__((ext_vector_type(8))) short bf16x8;

static __device__ __forceinline__ unsigned short f2bf(float f) {
    union { float f; unsigned u; } v; v.f = f;
    unsigned r = v.u + 0x7FFF + ((v.u >> 16) & 1);   // RNE
    return (unsigned short)(r >> 16);
}
static __device__ __forceinline__ float bf2f(unsigned short h) {
    union { float f; unsigned u; } v; v.u = ((unsigned)h) << 16; return v.f;
}

// ---------------------------------------------------------------------------
// Weight transpose -> separate hi/lo bf16 planes, k-major:
//   wh/wl [DEPTH][COUT_g][KFULL] ushort
// k row: cin<CC -> tap*CC+cin (x block) else KH + tap*HID + (cin-CC) (h block)
// n gate-gathered: n' = (r>>4)*64 + g*16 + (r&15)
// ---------------------------------------------------------------------------
__global__ void transpose_w_kernel(const float* __restrict__ w,
                                   unsigned short* __restrict__ wh,
                                   unsigned short* __restrict__ wl) {
    int idx = blockIdx.x * 256 + threadIdx.x;
    if (idx >= DEPTH * K9 * COUT) return;
    int n = idx % COUT;
    int k = (idx / COUT) % K9;
    int d = idx / (COUT * K9);
    int cin = k / 9, tap = k % 9;
    float v = w[(((long)(d * COUT + n) * CIN + cin) * 9) + tap];
    int row = (cin < CC) ? (tap * CC + cin) : (KH + tap * HID + (cin - CC));
    int g = n >> 7, r = n & 127;
    int ng = (r >> 4) * 64 + g * 16 + (r & 15);
    unsigned short hi = f2bf(v);
    unsigned short lo = f2bf(v - bf2f(hi));
    long o = ((long)d * COUT + ng) * KFULL + row;
    wh[o] = hi;
    wl[o] = lo;
}

// ---------------------------------------------------------------------------
// Pack x [B][S][CC][HW] fp32 -> hi/lo planes [s][b][hw][cc] via LDS transpose.
// grid (SS*BB, HW/64), 256 threads. Coalesced reads (float2 along hw) and
// coalesced u32 writes (along cc).
// ---------------------------------------------------------------------------
__global__ void pack_x_kernel(const float* __restrict__ x,
                              unsigned* __restrict__ xh32,
                              unsigned* __restrict__ xl32) {
    __shared__ unsigned lh[128 * 33], ll[128 * 33];   // [cc][hw-pair], pad 33
    const int tid = threadIdx.x;
    const int sb  = blockIdx.x;          // s*BB + b
    const int s   = sb >> 2;
    const int b   = sb & 3;
    const int hw0 = blockIdx.y * 64;
    const float* src = x + ((long)(b * SS + s) * CC) * HW;

    #pragma unroll
    for (int it = 0; it < 16; ++it) {
        int cc = it * 8 + (tid >> 5);
        int hw = (tid & 31) * 2;
        float2 v = *(const float2*)&src[cc * HW + hw0 + hw];
        unsigned short h0 = f2bf(v.x), h1 = f2bf(v.y);
        unsigned short l0 = f2bf(v.x - bf2f(h0)), l1 = f2bf(v.y - bf2f(h1));
        lh[cc * 33 + (hw >> 1)] = (unsigned)h0 | ((unsigned)h1 << 16);
        ll[cc * 33 + (hw >> 1)] = (unsigned)l0 | ((unsigned)l1 << 16);
    }
    __syncthreads();
    const unsigned short* lhs = (const unsigned short*)lh;
    const unsigned short* lls = (const unsigned short*)ll;
    #pragma unroll
    for (int it = 0; it < 16; ++it) {
        int hw = it * 4 + (tid >> 6);
        int c2 = tid & 63;               // cc pair
        unsigned short a0 = lhs[(2 * c2) * 66 + hw];
        unsigned short a1 = lhs[(2 * c2 + 1) * 66 + hw];
        unsigned short b0 = lls[(2 * c2) * 66 + hw];
        unsigned short b1 = lls[(2 * c2 + 1) * 66 + hw];
        long o = ((long)sb * HW + hw0 + hw) * 64 + c2;
        xh32[o] = (unsigned)a0 | ((unsigned)a1 << 16);
        xl32[o] = (unsigned)b0 | ((unsigned)b1 << 16);
    }
}

// ---------------------------------------------------------------------------
// Broadcast init_h/init_c[d] into hi/lo h planes ([b][hw][hid]) + fp32 c
// ---------------------------------------------------------------------------
__global__ void init_state_kernel(const float* __restrict__ ih, const float* __restrict__ ic,
                                  unsigned short* __restrict__ hh, unsigned short* __restrict__ hl,
                                  float* __restrict__ c, int d) {
    int idx = blockIdx.x * 256 + threadIdx.x;   // ACT = 262144
    int hid = idx & 127;
    float v = ih[d * HID + hid];
    unsigned short hi = f2bf(v);
    hh[idx] = hi;
    hl[idx] = f2bf(v - bf2f(hi));
    c[idx] = ic[d * HID + hid];
}

// Zero the 256B OOB page (workspace is poisoned 0xAA before timing)
__global__ void zero_kernel(unsigned* __restrict__ zp) { zp[threadIdx.x] = 0u; }

// ---------------------------------------------------------------------------
// DUAL-LAYER fused step kernel — 16x16x32 MFMA, 32x32 WAVE tiles (2x2 frags):
// 8 LDS reads : 12 MFMAs per k-sub (1.5:1 reuse vs round-13's 1:1) — attacks
// the LDS-read-BW bound. M=64, N=64 per wg, 256 threads = 4 waves (2m x 2n).
// BK=64 tiles, hi/lo planes pre-split, XOR-swizzled LDS (16-row frag reads =
// conflict-free), single barrier per tile, commit-after-compute dbuf,
// setprio around MFMA cluster. Grid 512 flat, XCD-stable swizzle.
// K = 36 tiles: tt<18 from x-source, tt>=18 from h-source (tap-major).
// ---------------------------------------------------------------------------
__launch_bounds__(256)
__global__ void step_dual(
    const unsigned short* __restrict__ x1h, const unsigned short* __restrict__ x1l,
    const unsigned short* __restrict__ h1h, const unsigned short* __restrict__ h1l,
    float* __restrict__ c1, unsigned short* __restrict__ o1h, unsigned short* __restrict__ o1l,
    const unsigned short* __restrict__ x2h, const unsigned short* __restrict__ x2l,
    const unsigned short* __restrict__ h2h, const unsigned short* __restrict__ h2l,
    float* __restrict__ c2, unsigned short* __restrict__ o2h, unsigned short* __restrict__ o2l,
    const unsigned short* __restrict__ wh, const unsigned short* __restrict__ wl,
    const float* __restrict__ bias, const unsigned short* __restrict__ zp,
    int do1, int do2)
{
    // buf layout (ushort idx): A_hi [0,4096) rows m*64+k, A_lo [4096,8192),
    // B_hi [8192,12288), B_lo [12288,16384). 2 bufs = 64 KB.
    __shared__ __align__(16) unsigned short lds[2][16384];

    const int bid  = blockIdx.x;
    const int xcd  = bid & 7;
    const int q    = bid >> 3;               // 0..63
    const int mblk = q & 31;
    const int pp   = xcd + ((q >> 5) << 3);  // panel 0..15
    const int nblk = pp & 7;
    const int z    = pp >> 3;
    if (z == 0) { if (!do1) return; } else { if (!do2) return; }

    const unsigned short* axh = z ? x2h : x1h;
    const unsigned short* axl = z ? x2l : x1l;
    const unsigned short* ahh = z ? h2h : h1h;
    const unsigned short* ahl = z ? h2l : h1l;
    const unsigned short* wph = wh + (long)z * COUT * KFULL;
    const unsigned short* wpl = wl + (long)z * COUT * KFULL;
    const float* bsel  = bias + z * COUT;
    float* csel        = z ? c2 : c1;
    unsigned short* ohh = z ? o2h : o1h;
    unsigned short* ohl = z ? o2l : o1l;

    const int m0   = mblk * 64;
    const int n0g  = nblk * 64;
    const int hid0 = nblk * 16;
    const int tid  = threadIdx.x;
    const int lane = tid & 63;
    const int wv   = tid >> 6;              // wave 0..3
    const int wm   = (wv >> 1) * 32;        // wave m offset (32x32 tile)
    const int wn   = (wv & 1) * 32;         // wave n offset
    const int b    = m0 >> 9;
    const int hwl  = m0 & 511;
    const int y0   = hwl >> 5;              // first image row (2 rows per wg)

    // staging: thread t: row r = t>>2 (0..63), chunks j0 = t&3, j1 = j0+4;
    // source chunk = j ^ (r&7) (XOR swizzle), LDS chunk = j (linear)
    const int r    = tid >> 2;
    const int j0   = tid & 3;
    const int jx0  = j0 ^ (r & 7);
    const int jx1  = (j0 + 4) ^ (r & 7);
    const int sx   = r & 31;
    const int sy   = y0 + (r >> 5);
    const long bhw = (long)b * HW;
    const long bofs = (long)(n0g + r) * KFULL;
    const int seg0 = r * 64 + j0 * 8;
    const int seg1 = seg0 + 32;

    uint4 rah0, rah1, ral0, ral1, rbh0, rbh1, rbl0, rbl1;
    auto ld = [&](int tt) {
        const int k0 = tt * 64;
        rbh0 = *(const uint4*)(wph + bofs + k0 + jx0 * 8);
        rbh1 = *(const uint4*)(wph + bofs + k0 + jx1 * 8);
        rbl0 = *(const uint4*)(wpl + bofs + k0 + jx0 * 8);
        rbl1 = *(const uint4*)(wpl + bofs + k0 + jx1 * 8);
        int ksub = (tt < 18) ? tt : tt - 18;
        int tap  = ksub >> 1;
        int c0   = (ksub & 1) << 6;
        int ky   = tap / 3 - 1;
        int kx   = tap - (tap / 3) * 3 - 1;
        int yy   = sy + ky;
        int xq   = sx + kx;
        bool ok  = (unsigned)yy < (unsigned)HH && (unsigned)xq < (unsigned)WW;
        long abase = ((bhw + yy * WW + xq) << 7) + c0;
        const unsigned short* sh = (tt < 18) ? axh : ahh;
        const unsigned short* sl = (tt < 18) ? axl : ahl;
        const unsigned short* p0h = ok ? sh + abase + jx0 * 8 : zp;
        const unsigned short* p1h = ok ? sh + abase + jx1 * 8 : zp;
        const unsigned short* p0l = ok ? sl + abase + jx0 * 8 : zp;
        const unsigned short* p1l = ok ? sl + abase + jx1 * 8 : zp;
        rah0 = *(const uint4*)p0h; rah1 = *(const uint4*)p1h;
        ral0 = *(const uint4*)p0l; ral1 = *(const uint4*)p1l;
    };
    auto commit = [&](int pb) {
        *(uint4*)&lds[pb][seg0]         = rah0;
        *(uint4*)&lds[pb][seg1]         = rah1;
        *(uint4*)&lds[pb][4096 + seg0]  = ral0;
        *(uint4*)&lds[pb][4096 + seg1]  = ral1;
        *(uint4*)&lds[pb][8192 + seg0]  = rbh0;
        *(uint4*)&lds[pb][8192 + seg1]  = rbh1;
        *(uint4*)&lds[pb][12288 + seg0] = rbl0;
        *(uint4*)&lds[pb][12288 + seg1] = rbl1;
    };

    f32x4 acc00 = (f32x4){0.f,0.f,0.f,0.f};
    f32x4 acc01 = (f32x4){0.f,0.f,0.f,0.f};
    f32x4 acc10 = (f32x4){0.f,0.f,0.f,0.f};
    f32x4 acc11 = (f32x4){0.f,0.f,0.f,0.f};

    const int fr  = lane & 15;
    const int kqi = lane >> 4;              // 0..3 (k chunk within sub)
    const int am0 = wm + fr;                // A rows (2 m-frags)
    const int am1 = wm + 16 + fr;
    const int bn0 = wn + fr;                // B rows (2 n-frags)
    const int bn1 = wn + 16 + fr;

    ld(0); commit(0);
    __syncthreads();
    int p = 0;
    for (int tt = 0; tt < 36; ++tt) {
        const bool more = (tt + 1 < 36);
        if (more) ld(tt + 1);               // loads in flight during compute
        const unsigned short* L = &lds[p][0];
        __builtin_amdgcn_s_setprio(1);
        #pragma unroll
        for (int s = 0; s < 2; ++s) {
            const int ca = s * 4 + kqi;     // chunk 0..7
            bf16x8 ah0 = *(const bf16x8*)&L[am0 * 64 + ((ca ^ (am0 & 7)) << 3)];
            bf16x8 ah1 = *(const bf16x8*)&L[am1 * 64 + ((ca ^ (am1 & 7)) << 3)];
            bf16x8 al0 = *(const bf16x8*)&L[4096 + am0 * 64 + ((ca ^ (am0 & 7)) << 3)];
            bf16x8 al1 = *(const bf16x8*)&L[4096 + am1 * 64 + ((ca ^ (am1 & 7)) << 3)];
            bf16x8 bh0 = *(const bf16x8*)&L[8192 + bn0 * 64 + ((ca ^ (bn0 & 7)) << 3)];
            bf16x8 bh1 = *(const bf16x8*)&L[8192 + bn1 * 64 + ((ca ^ (bn1 & 7)) << 3)];
            bf16x8 bl0 = *(const bf16x8*)&L[12288 + bn0 * 64 + ((ca ^ (bn0 & 7)) << 3)];
            bf16x8 bl1 = *(const bf16x8*)&L[12288 + bn1 * 64 + ((ca ^ (bn1 & 7)) << 3)];
            acc00 = __builtin_amdgcn_mfma_f32_16x16x32_bf16(ah0, bh0, acc00, 0, 0, 0);
            acc01 = __builtin_amdgcn_mfma_f32_16x16x32_bf16(ah0, bh1, acc01, 0, 0, 0);
            acc10 = __builtin_amdgcn_mfma_f32_16x16x32_bf16(ah1, bh0, acc10, 0, 0, 0);
            acc11 = __builtin_amdgcn_mfma_f32_16x16x32_bf16(ah1, bh1, acc11, 0, 0, 0);
            acc00 = __builtin_amdgcn_mfma_f32_16x16x32_bf16(ah0, bl0, acc00, 0, 0, 0);
            acc01 = __builtin_amdgcn_mfma_f32_16x16x32_bf16(ah0, bl1, acc01, 0, 0, 0);
            acc10 = __builtin_amdgcn_mfma_f32_16x16x32_bf16(ah1, bl0, acc10, 0, 0, 0);
            acc11 = __builtin_amdgcn_mfma_f32_16x16x32_bf16(ah1, bl1, acc11, 0, 0, 0);
            acc00 = __builtin_amdgcn_mfma_f32_16x16x32_bf16(al0, bh0, acc00, 0, 0, 0);
            acc01 = __builtin_amdgcn_mfma_f32_16x16x32_bf16(al0, bh1, acc01, 0, 0, 0);
            acc10 = __builtin_amdgcn_mfma_f32_16x16x32_bf16(al1, bh0, acc10, 0, 0, 0);
            acc11 = __builtin_amdgcn_mfma_f32_16x16x32_bf16(al1, bh1, acc11, 0, 0, 0);
        }
        __builtin_amdgcn_s_setprio(0);
        if (more) commit(1 - p);            // write NEXT buffer after compute
        __syncthreads();                    // one barrier per tile
        p ^= 1;
    }

    // --- epilogue: z-tile via LDS (reuse buffer 0), then LSTM cell update ---
    float* zt = (float*)&lds[0][0];         // [64 n_gathered][68 m]
    {
        const int rm = (lane >> 4) * 4;
        const int cn = lane & 15;
        *(float4*)&zt[(wn + cn) * 68 + wm + rm]           = *(float4*)&acc00;
        *(float4*)&zt[(wn + 16 + cn) * 68 + wm + rm]      = *(float4*)&acc01;
        *(float4*)&zt[(wn + cn) * 68 + wm + 16 + rm]      = *(float4*)&acc10;
        *(float4*)&zt[(wn + 16 + cn) * 68 + wm + 16 + rm] = *(float4*)&acc11;
    }
    __syncthreads();

    #pragma unroll
    for (int i2 = 0; i2 < 4; ++i2) {        // 1024 cell elems, 4/thread
        int e  = i2 * 256 + tid;
        int m  = e & 63;
        int jh = e >> 6;                    // hid slice 0..15
        float g4[4];
        #pragma unroll
        for (int gi = 0; gi < 4; ++gi)
            g4[gi] = zt[(gi * 16 + jh) * 68 + m] + bsel[gi * 128 + hid0 + jh];
        long idx = ((long)b * HW + hwl + m) * 128 + hid0 + jh;
        float si = 1.f / (1.f + expf(-g4[0]));
        float sf = 1.f / (1.f + expf(-g4[1]));
        float so = 1.f / (1.f + expf(-g4[3]));
        float cs = sf * csel[idx] + si * tanhf(g4[2]);
        float hs = so * tanhf(cs);
        csel[idx] = cs;
        unsigned short hi = f2bf(hs);
        ohh[idx] = hi;
        ohl[idx] = f2bf(hs - bf2f(hi));
    }
}

// ---------------------------------------------------------------------------
// Mean pool over HW: seq2 planes [s][b][hw][hid] -> pooled [(s*BB+b)*HID + j]
// ---------------------------------------------------------------------------
__global__ void pool_kernel(const unsigned short* __restrict__ s2h,
                            const unsigned short* __restrict__ s2l,
                            float* __restrict__ pooled) {
    int bs = blockIdx.x;            // s*BB + b
    int j  = threadIdx.x;           // 0..127
    const unsigned short* ph = s2h + (long)bs * HW * 128 + j;
    const unsigned short* pl = s2l + (long)bs * HW * 128 + j;
    float sum = 0.f;
    #pragma unroll 8
    for (int hw = 0; hw < HW; ++hw)
        sum += bf2f(ph[hw * 128]) + bf2f(pl[hw * 128]);
    pooled[bs * HID + j] = sum * (1.f / HW);
}

// ---------------------------------------------------------------------------
// FC + ReLU + two scalar heads.
// ---------------------------------------------------------------------------
__global__ void head_kernel(const float* __restrict__ pooled,
                            const float* __restrict__ fc_w, const float* __restrict__ fc_b,
                            const float* __restrict__ fco_w, const float* __restrict__ fco_b,
                            const float* __restrict__ fca_w, const float* __restrict__ fca_b,
                            float* __restrict__ out) {
    int bs = blockIdx.x;          // b*S + s
    int b  = bs / SS;
    int s  = bs % SS;
    int j  = threadIdx.x;
    const float* prow = pooled + (long)(s * BB + b) * HID;
    float acc = fc_b[j];
    #pragma unroll 4
    for (int k = 0; k < HID; ++k) acc += fc_w[j * HID + k] * prow[k];
    float f = fmaxf(acc, 0.f);
    __shared__ float ro[128], ra[128];
    ro[j] = f * fco_w[j];
    ra[j] = f * fca_w[j];
    __syncthreads();
    for (int off = 64; off; off >>= 1) {
        if (j < off) { ro[j] += ro[j + off]; ra[j] += ra[j + off]; }
        __syncthreads();
    }
    if (j == 0) {
        out[bs]           = ro[0] + fco_b[0];
        out[BB * SS + bs] = ra[0] + fca_b[0];
    }
}

// ---------------------------------------------------------------------------
extern "C" void kernel_launch(void* const* d_in, const int* in_sizes, int n_in,
                              void* d_out, int out_size, void* d_ws, size_t ws_size,
                              hipStream_t stream) {
    const float* x      = (const float*)d_in[0];
    const float* conv_w = (const float*)d_in[1];
    const float* conv_b = (const float*)d_in[2];
    const float* init_h = (const float*)d_in[3];
    const float* init_c = (const float*)d_in[4];
    const float* fc_w   = (const float*)d_in[5];
    const float* fc_b   = (const float*)d_in[6];
    const float* fco_w  = (const float*)d_in[7];
    const float* fco_b  = (const float*)d_in[8];
    const float* fca_w  = (const float*)d_in[9];
    const float* fca_b  = (const float*)d_in[10];
    float* out = (float*)d_out;

    // Workspace carve-up (ushort planes first, then fp32) — total ~114 MB.
    unsigned short* wh  = (unsigned short*)d_ws;            // 2,359,296
    unsigned short* wl  = wh  + (long)DEPTH * COUT * KFULL; // 2,359,296
    unsigned short* xph = wl  + (long)DEPTH * COUT * KFULL; // SS*ACT = 8,388,608
    unsigned short* xpl = xph + (long)SS * ACT;
    unsigned short* s1h = xpl + (long)SS * ACT;
    unsigned short* s1l = s1h + (long)SS * ACT;
    unsigned short* s2h = s1l + (long)SS * ACT;
    unsigned short* s2l = s2h + (long)SS * ACT;
    unsigned short* h1h = s2l + (long)SS * ACT;             // ACT each
    unsigned short* h1l = h1h + ACT;
    unsigned short* h2h = h1l + ACT;
    unsigned short* h2l = h2h + ACT;
    float* c1     = (float*)(h2l + ACT);                    // ACT f32
    float* c2     = c1 + ACT;
    float* pooled = c2 + ACT;                               // 16,384
    unsigned short* zp = (unsigned short*)(pooled + SS * BB * HID); // 256 B zeros

    transpose_w_kernel<<<(DEPTH * K9 * COUT + 255) / 256, 256, 0, stream>>>(conv_w, wh, wl);
    pack_x_kernel<<<dim3(SS * BB, HW / 64), 256, 0, stream>>>(x, (unsigned*)xph, (unsigned*)xpl);
    init_state_kernel<<<ACT / 256, 256, 0, stream>>>(init_h, init_c, h1h, h1l, c1, 0);
    init_state_kernel<<<ACT / 256, 256, 0, stream>>>(init_h, init_c, h2h, h2l, c2, 1);
    zero_kernel<<<1, 64, 0, stream>>>((unsigned*)zp);

    for (int t = 0; t <= SS; ++t) {
        int do1 = (t < SS) ? 1 : 0;
        int do2 = (t >= 1) ? 1 : 0;
        int t1 = (t < SS) ? t : SS - 1;          // clamped for safe ptr arith
        int u2 = (t >= 1) ? t - 1 : 0;
        const unsigned short* ax1h = xph + (long)t1 * ACT;
        const unsigned short* ax1l = xpl + (long)t1 * ACT;
        const unsigned short* ah1h = (t1 == 0) ? h1h : s1h + (long)(t1 - 1) * ACT;
        const unsigned short* ah1l = (t1 == 0) ? h1l : s1l + (long)(t1 - 1) * ACT;
        unsigned short* ao1h = s1h + (long)t1 * ACT;
        unsigned short* ao1l = s1l + (long)t1 * ACT;
        const unsigned short* ax2h = s1h + (long)u2 * ACT;
        const unsigned short* ax2l = s1l + (long)u2 * ACT;
        const unsigned short* ah2h = (u2 == 0) ? h2h : s2h + (long)(u2 - 1) * ACT;
        const unsigned short* ah2l = (u2 == 0) ? h2l : s2l + (long)(u2 - 1) * ACT;
        unsigned short* ao2h = s2h + (long)u2 * ACT;
        unsigned short* ao2l = s2l + (long)u2 * ACT;
        step_dual<<<512, 256, 0, stream>>>(
            ax1h, ax1l, ah1h, ah1l, c1, ao1h, ao1l,
            ax2h, ax2l, ah2h, ah2l, c2, ao2h, ao2l,
            wh, wl, conv_b, zp, do1, do2);
    }

    pool_kernel<<<SS * BB, 128, 0, stream>>>(s2h, s2l, pooled);
    head_kernel<<<BB * SS, 128, 0, stream>>>(pooled, fc_w, fc_b, fco_w, fco_b, fca_w, fca_b, out);
}